// Round 1
// baseline (6306.580 us; speedup 1.0000x reference)
//
#include <hip/hip_runtime.h>
#include <math.h>

#define Bsz 2
#define Tsz 2048
#define Esz 1024
#define Hsz 16
#define Vsz 32000
#define Dsz 64
#define BT  (Bsz*Tsz)   // 4096

typedef __attribute__((ext_vector_type(4))) float f32x4;
typedef __attribute__((ext_vector_type(8))) __bf16 bf16x8;

__device__ __forceinline__ unsigned short f2bf(float f) {
    unsigned int u = __float_as_uint(f);
    u += 0x7fffu + ((u >> 16) & 1u);   // round-to-nearest-even
    return (unsigned short)(u >> 16);
}

// ---------------- fp32 -> bf16 cast, 4 elems/thread
__global__ __launch_bounds__(256) void cast_bf16_kernel(const float* __restrict__ in,
                                                        unsigned short* __restrict__ out,
                                                        int n4) {
    int i = blockIdx.x * 256 + threadIdx.x;
    if (i >= n4) return;
    float4 f = ((const float4*)in)[i];
    ushort4 u;
    u.x = f2bf(f.x); u.y = f2bf(f.y); u.z = f2bf(f.z); u.w = f2bf(f.w);
    ((ushort4*)out)[i] = u;
}

// ---------------- embedding: x16[bt,e] = bf16(tok_table[tokens[bt],e] + pos_emb[t,e])
__global__ __launch_bounds__(256) void embed_bf16_kernel(const int* __restrict__ tokens,
                                                         const float* __restrict__ tok_table,
                                                         const float* __restrict__ pos_emb,
                                                         unsigned short* __restrict__ x16) {
    int i = blockIdx.x * 256 + threadIdx.x;   // over BT*E/4
    int g = i * 4;
    int e  = g & (Esz - 1);
    int bt = g >> 10;
    int t  = bt & (Tsz - 1);
    float4 a = *(const float4*)&tok_table[(size_t)tokens[bt] * Esz + e];
    float4 p = *(const float4*)&pos_emb[(size_t)t * Esz + e];
    ushort4 u;
    u.x = f2bf(a.x + p.x); u.y = f2bf(a.y + p.y);
    u.z = f2bf(a.z + p.z); u.w = f2bf(a.w + p.w);
    *(ushort4*)&x16[g] = u;
}

// ---------------- bf16 MFMA GEMM (m97 structure): C[m,n] = sum_k A[m,k]*W[n,k] + bias[n]
// A:[M,K] bf16 row-major, W:[N,K] bf16 row-major ("B^T input"), C fp32.
// MODE 0: C row-major [M,N].  MODE 1: scatter to q/k/v [B,H,T,D] with n=h*64+d, m=b*T+t.
#define GLD_LDS(gp, lp) __builtin_amdgcn_global_load_lds( \
    (const __attribute__((address_space(1))) void*)(gp),  \
    (__attribute__((address_space(3))) void*)(lp), 16, 0, 0)

template <int MODE>
__global__ __launch_bounds__(256) void gemm_mfma(const unsigned short* __restrict__ A,
                                                 const unsigned short* __restrict__ W,
                                                 const float* __restrict__ bias,
                                                 float* __restrict__ C,
                                                 int M, int N, int K) {
    constexpr int BK = 32;
    __shared__ __align__(16) unsigned short As[128 * BK];   // 8 KB
    __shared__ __align__(16) unsigned short Bs[128 * BK];   // 8 KB
    const int tid  = threadIdx.x;
    const int lane = tid & 63;
    const int wid  = tid >> 6;            // 4 waves, 2x2 over the 128x128 tile
    const int row0 = blockIdx.y * 128;
    const int col0 = blockIdx.x * 128;
    const int wr = (wid >> 1) * 64;
    const int wc = (wid & 1) * 64;

    // staging: per wave-instruction, 64 lanes x 16B = 16 rows x 32 bf16 (linear LDS dest)
    const int srow = lane >> 2;           // 0..15
    const int scol = (lane & 3) * 8;      // 0,8,16,24 (bf16 elems)
    const unsigned short* Ab = A + (size_t)row0 * K;
    const unsigned short* Wb = W + (size_t)col0 * K;

    const int fr = lane & 15;             // fragment row/col within 16
    const int kh = (lane >> 4) * 8;       // k-slice per 16-lane group

    f32x4 acc[4][4] = {};

    for (int k0 = 0; k0 < K; k0 += BK) {
#pragma unroll
        for (int i = 0; i < 2; ++i) {
            const int r = wid * 32 + i * 16;
            GLD_LDS(Ab + (size_t)(r + srow) * K + k0 + scol, &As[r * BK]);
            GLD_LDS(Wb + (size_t)(r + srow) * K + k0 + scol, &Bs[r * BK]);
        }
        __syncthreads();   // compiler drains vmcnt(0) before barrier -> LDS tile ready
        bf16x8 af[4], bfr[4];
#pragma unroll
        for (int m = 0; m < 4; ++m) af[m]  = *(const bf16x8*)&As[(wr + m * 16 + fr) * BK + kh];
#pragma unroll
        for (int n = 0; n < 4; ++n) bfr[n] = *(const bf16x8*)&Bs[(wc + n * 16 + fr) * BK + kh];
#pragma unroll
        for (int m = 0; m < 4; ++m)
#pragma unroll
            for (int n = 0; n < 4; ++n)
                acc[m][n] = __builtin_amdgcn_mfma_f32_16x16x32_bf16(af[m], bfr[n], acc[m][n], 0, 0, 0);
        __syncthreads();
    }

    // epilogue: C/D layout col=lane&15, row=(lane>>4)*4+j (m89-verified)
    const int rq = (lane >> 4) * 4;
#pragma unroll
    for (int n = 0; n < 4; ++n) {
        const int gn = col0 + wc + n * 16 + fr;
        const float bv = bias[gn];
#pragma unroll
        for (int m = 0; m < 4; ++m) {
#pragma unroll
            for (int j = 0; j < 4; ++j) {
                const int gm = row0 + wr + m * 16 + rq + j;
                const float val = acc[m][n][j] + bv;
                if (MODE == 0) {
                    C[(size_t)gm * N + gn] = val;
                } else {
                    const int b = gm >> 11, t = gm & (Tsz - 1);
                    const int h = gn >> 6,  d = gn & 63;
                    C[((((size_t)b * Hsz + h) * Tsz + t) << 6) + d] = val;
                }
            }
        }
    }
}

// ---------------- attention: one block per (b,h,t) row; scores in LDS; two-pass softmax
// unchanged numerics (fp32 q/k/v), output stored as bf16 for the logits GEMM
__global__ __launch_bounds__(256) void attn_kernel(const float* __restrict__ q,
                                                   const float* __restrict__ k,
                                                   const float* __restrict__ v,
                                                   unsigned short* __restrict__ o16) {
    __shared__ float sc[Tsz];
    __shared__ float qs[Dsz];
    __shared__ float red[256];
    __shared__ float oacc[256];

    const int bi = blockIdx.x;            // (b*H+h)*T + t
    const int t  = bi & (Tsz - 1);
    const int bh = bi >> 11;              // b*H + h
    const int h  = bh & (Hsz - 1);
    const int b  = bh >> 4;
    const int tid = threadIdx.x;
    const int lane = tid & 63;
    const int wv = tid >> 6;              // 4 waves

    if (tid < Dsz) qs[tid] = q[((size_t)bh * Tsz + t) * Dsz + tid];
    __syncthreads();

    const int nS = t + 1;
    // phase 1: raw scores with faithful mask quirk
    for (int s = wv; s < nS; s += 4) {
        float p = qs[lane] * k[((size_t)bh * Tsz + s) * Dsz + lane];
#pragma unroll
        for (int off = 32; off > 0; off >>= 1) p += __shfl_down(p, off, 64);
        if (lane == 0) {
            if (p == 0.0f) p = -INFINITY;   // reference: w==0 -> -inf
            sc[s] = p;
        }
    }
    __syncthreads();

    // max
    float mx = -INFINITY;
    for (int s = tid; s < nS; s += 256) mx = fmaxf(mx, sc[s]);
    red[tid] = mx; __syncthreads();
    for (int st = 128; st > 0; st >>= 1) { if (tid < st) red[tid] = fmaxf(red[tid], red[tid + st]); __syncthreads(); }
    mx = red[0]; __syncthreads();

    // exp + sum
    float sm = 0.0f;
    for (int s = tid; s < nS; s += 256) { float e = expf(sc[s] - mx); sc[s] = e; sm += e; }
    red[tid] = sm; __syncthreads();
    for (int st = 128; st > 0; st >>= 1) { if (tid < st) red[tid] += red[tid + st]; __syncthreads(); }
    const float scale = 1.0f / (red[0] * 8.0f);   // softmax denom * sqrt(D)
    __syncthreads();

    // phase 2: o[d] = scale * sum_s sc[s]*v[s,d]
    const int d = tid & 63, part = tid >> 6;
    float acc = 0.0f;
    for (int s = part; s < nS; s += 4) acc += sc[s] * v[((size_t)bh * Tsz + s) * Dsz + d];
    oacc[tid] = acc; __syncthreads();
    if (tid < 64) {
        float tot = (oacc[tid] + oacc[64 + tid]) + (oacc[128 + tid] + oacc[192 + tid]);
        o16[((size_t)(b * Tsz + t)) * Esz + h * Dsz + d] = f2bf(tot * scale);
    }
}

// ---------------- per-row NLL: rl[row] = lse(logits[row,:]) - logits[row,target]
__global__ __launch_bounds__(256) void rowloss_kernel(const float* __restrict__ logits,
                                                      const int* __restrict__ targets,
                                                      float* __restrict__ rl) {
    const int row = blockIdx.x;
    const float* lr = logits + (size_t)row * Vsz;
    __shared__ float red[256];
    const int tid = threadIdx.x;
    float m = -INFINITY;
    for (int i = tid; i < Vsz; i += 256) m = fmaxf(m, lr[i]);
    red[tid] = m; __syncthreads();
    for (int st = 128; st > 0; st >>= 1) { if (tid < st) red[tid] = fmaxf(red[tid], red[tid + st]); __syncthreads(); }
    m = red[0]; __syncthreads();
    float s = 0.0f;
    for (int i = tid; i < Vsz; i += 256) s += expf(lr[i] - m);
    red[tid] = s; __syncthreads();
    for (int st = 128; st > 0; st >>= 1) { if (tid < st) red[tid] += red[tid + st]; __syncthreads(); }
    if (tid == 0) rl[row] = (m + logf(red[0])) - lr[targets[row]];
}

__global__ __launch_bounds__(256) void loss_reduce_kernel(const float* __restrict__ rl,
                                                          float* __restrict__ out_loss) {
    __shared__ float red[256];
    const int tid = threadIdx.x;
    float s = 0.0f;
    for (int i = tid; i < BT; i += 256) s += rl[i];
    red[tid] = s; __syncthreads();
    for (int st = 128; st > 0; st >>= 1) { if (tid < st) red[tid] += red[tid + st]; __syncthreads(); }
    if (tid == 0) out_loss[0] = red[0] / (float)BT;
}

extern "C" void kernel_launch(void* const* d_in, const int* in_sizes, int n_in,
                              void* d_out, int out_size, void* d_ws, size_t ws_size,
                              hipStream_t stream) {
    const int*   tokens    = (const int*)d_in[0];
    const int*   targets   = (const int*)d_in[1];
    const float* tok_table = (const float*)d_in[2];
    const float* pos_emb   = (const float*)d_in[3];
    const float* Wq        = (const float*)d_in[4];
    const float* bq        = (const float*)d_in[5];
    const float* Wk        = (const float*)d_in[6];
    const float* bk        = (const float*)d_in[7];
    const float* Wv        = (const float*)d_in[8];
    const float* bv        = (const float*)d_in[9];
    const float* Wo        = (const float*)d_in[10];
    const float* bo        = (const float*)d_in[11];

    float* out    = (float*)d_out;
    float* logits = out;                              // [BT, V]
    float* loss   = out + (size_t)BT * Vsz;           // scalar

    char* p = (char*)d_ws;
    unsigned short* x16  = (unsigned short*)p; p += (size_t)BT * Esz * 2;   // 8 MB
    float*          q    = (float*)p;          p += (size_t)BT * Esz * 4;   // 16 MB
    float*          k    = (float*)p;          p += (size_t)BT * Esz * 4;   // 16 MB
    float*          v    = (float*)p;          p += (size_t)BT * Esz * 4;   // 16 MB
    unsigned short* o16  = (unsigned short*)p; p += (size_t)BT * Esz * 2;   // 8 MB
    unsigned short* wq16 = (unsigned short*)p; p += (size_t)Esz * Esz * 2;  // 2 MB
    unsigned short* wk16 = (unsigned short*)p; p += (size_t)Esz * Esz * 2;  // 2 MB
    unsigned short* wv16 = (unsigned short*)p; p += (size_t)Esz * Esz * 2;  // 2 MB
    unsigned short* wo16 = (unsigned short*)p; p += (size_t)Vsz * Esz * 2;  // 65.5 MB
    float*          rl   = (float*)p;

    // 1) embedding (bf16 out) + weight casts
    embed_bf16_kernel<<<(BT * Esz / 4) / 256, 256, 0, stream>>>(tokens, tok_table, pos_emb, x16);
    cast_bf16_kernel<<<(Esz * Esz / 4) / 256, 256, 0, stream>>>(Wq, wq16, Esz * Esz / 4);
    cast_bf16_kernel<<<(Esz * Esz / 4) / 256, 256, 0, stream>>>(Wk, wk16, Esz * Esz / 4);
    cast_bf16_kernel<<<(Esz * Esz / 4) / 256, 256, 0, stream>>>(Wv, wv16, Esz * Esz / 4);
    cast_bf16_kernel<<<(Vsz * Esz / 4) / 256, 256, 0, stream>>>(Wo, wo16, Vsz * Esz / 4);

    // 2) QKV projections -> [B,H,T,D] fp32
    dim3 gqkv(Esz / 128, BT / 128);
    gemm_mfma<1><<<gqkv, 256, 0, stream>>>(x16, wq16, bq, q, BT, Esz, Esz);
    gemm_mfma<1><<<gqkv, 256, 0, stream>>>(x16, wk16, bk, k, BT, Esz, Esz);
    gemm_mfma<1><<<gqkv, 256, 0, stream>>>(x16, wv16, bv, v, BT, Esz, Esz);

    // 3) attention (one block per (b,h,t)), emits bf16 o
    attn_kernel<<<Bsz * Hsz * Tsz, 256, 0, stream>>>(q, k, v, o16);

    // 4) logits GEMM [BT,V] via bf16 MFMA
    dim3 glog(Vsz / 128, BT / 128);
    gemm_mfma<0><<<glog, 256, 0, stream>>>(o16, wo16, bo, logits, BT, Vsz, Esz);

    // 5) loss
    rowloss_kernel<<<BT, 256, 0, stream>>>(logits, targets, rl);
    loss_reduce_kernel<<<1, 256, 0, stream>>>(rl, loss);
}

// Round 2
// 1460.418 us; speedup vs baseline: 4.3183x; 4.3183x over previous
//
#include <hip/hip_runtime.h>
#include <math.h>

#define Bsz 2
#define Tsz 2048
#define Esz 1024
#define Hsz 16
#define Vsz 32000
#define Dsz 64
#define BT  (Bsz*Tsz)   // 4096

typedef __attribute__((ext_vector_type(4))) float f32x4;
typedef __attribute__((ext_vector_type(8))) __bf16 bf16x8;

__device__ __forceinline__ unsigned short f2bf(float f) {
    unsigned int u = __float_as_uint(f);
    u += 0x7fffu + ((u >> 16) & 1u);   // round-to-nearest-even
    return (unsigned short)(u >> 16);
}

// ---------------- fp32 -> bf16 cast, 4 elems/thread
__global__ __launch_bounds__(256) void cast_bf16_kernel(const float* __restrict__ in,
                                                        unsigned short* __restrict__ out,
                                                        int n4) {
    int i = blockIdx.x * 256 + threadIdx.x;
    if (i >= n4) return;
    float4 f = ((const float4*)in)[i];
    ushort4 u;
    u.x = f2bf(f.x); u.y = f2bf(f.y); u.z = f2bf(f.z); u.w = f2bf(f.w);
    ((ushort4*)out)[i] = u;
}

// ---------------- embedding: x16[bt,e] = bf16(tok_table[tokens[bt],e] + pos_emb[t,e])
__global__ __launch_bounds__(256) void embed_bf16_kernel(const int* __restrict__ tokens,
                                                         const float* __restrict__ tok_table,
                                                         const float* __restrict__ pos_emb,
                                                         unsigned short* __restrict__ x16) {
    int i = blockIdx.x * 256 + threadIdx.x;   // over BT*E/4
    int g = i * 4;
    int e  = g & (Esz - 1);
    int bt = g >> 10;
    int t  = bt & (Tsz - 1);
    float4 a = *(const float4*)&tok_table[(size_t)tokens[bt] * Esz + e];
    float4 p = *(const float4*)&pos_emb[(size_t)t * Esz + e];
    ushort4 u;
    u.x = f2bf(a.x + p.x); u.y = f2bf(a.y + p.y);
    u.z = f2bf(a.z + p.z); u.w = f2bf(a.w + p.w);
    *(ushort4*)&x16[g] = u;
}

// ---------------- bf16 MFMA GEMM (m97 structure): C[m,n] = sum_k A[m,k]*W[n,k] + bias[n]
// A:[M,K] bf16 row-major, W:[N,K] bf16 row-major ("B^T input").
// MODE 0: C fp32 row-major [M,N].
// MODE 1: C bf16 scatter [B,H,T,D]  (n=h*64+d, m=b*T+t)
// MODE 2: C bf16 scatter [B,H,D,T]  (V^T for flash attention)
#define GLD_LDS(gp, lp) __builtin_amdgcn_global_load_lds( \
    (const __attribute__((address_space(1))) void*)(gp),  \
    (__attribute__((address_space(3))) void*)(lp), 16, 0, 0)

template <int MODE>
__global__ __launch_bounds__(256) void gemm_mfma(const unsigned short* __restrict__ A,
                                                 const unsigned short* __restrict__ W,
                                                 const float* __restrict__ bias,
                                                 void* __restrict__ Cout,
                                                 int M, int N, int K) {
    constexpr int BK = 32;
    __shared__ __align__(16) unsigned short As[128 * BK];   // 8 KB
    __shared__ __align__(16) unsigned short Bs[128 * BK];   // 8 KB
    const int tid  = threadIdx.x;
    const int lane = tid & 63;
    const int wid  = tid >> 6;            // 4 waves, 2x2 over the 128x128 tile
    const int row0 = blockIdx.y * 128;
    const int col0 = blockIdx.x * 128;
    const int wr = (wid >> 1) * 64;
    const int wc = (wid & 1) * 64;

    const int srow = lane >> 2;           // 0..15
    const int scol = (lane & 3) * 8;      // 0,8,16,24 (bf16 elems)
    const unsigned short* Ab = A + (size_t)row0 * K;
    const unsigned short* Wb = W + (size_t)col0 * K;

    const int fr = lane & 15;             // fragment row/col within 16
    const int kh = (lane >> 4) * 8;       // k-slice per 16-lane group

    f32x4 acc[4][4] = {};

    for (int k0 = 0; k0 < K; k0 += BK) {
#pragma unroll
        for (int i = 0; i < 2; ++i) {
            const int r = wid * 32 + i * 16;
            GLD_LDS(Ab + (size_t)(r + srow) * K + k0 + scol, &As[r * BK]);
            GLD_LDS(Wb + (size_t)(r + srow) * K + k0 + scol, &Bs[r * BK]);
        }
        __syncthreads();
        bf16x8 af[4], bfr[4];
#pragma unroll
        for (int m = 0; m < 4; ++m) af[m]  = *(const bf16x8*)&As[(wr + m * 16 + fr) * BK + kh];
#pragma unroll
        for (int n = 0; n < 4; ++n) bfr[n] = *(const bf16x8*)&Bs[(wc + n * 16 + fr) * BK + kh];
#pragma unroll
        for (int m = 0; m < 4; ++m)
#pragma unroll
            for (int n = 0; n < 4; ++n)
                acc[m][n] = __builtin_amdgcn_mfma_f32_16x16x32_bf16(af[m], bfr[n], acc[m][n], 0, 0, 0);
        __syncthreads();
    }

    // epilogue: C/D layout col=lane&15, row=(lane>>4)*4+j (m89-verified)
    const int rq = (lane >> 4) * 4;
#pragma unroll
    for (int n = 0; n < 4; ++n) {
        const int gn = col0 + wc + n * 16 + fr;
        const float bv = bias[gn];
        if (MODE == 0) {
            float* C = (float*)Cout;
#pragma unroll
            for (int m = 0; m < 4; ++m)
#pragma unroll
                for (int j = 0; j < 4; ++j) {
                    const int gm = row0 + wr + m * 16 + rq + j;
                    C[(size_t)gm * N + gn] = acc[m][n][j] + bv;
                }
        } else if (MODE == 1) {
            unsigned short* C = (unsigned short*)Cout;
#pragma unroll
            for (int m = 0; m < 4; ++m)
#pragma unroll
                for (int j = 0; j < 4; ++j) {
                    const int gm = row0 + wr + m * 16 + rq + j;
                    const int b = gm >> 11, t = gm & (Tsz - 1);
                    const int h = gn >> 6,  d = gn & 63;
                    C[((((size_t)b * Hsz + h) * Tsz + t) << 6) + d] = f2bf(acc[m][n][j] + bv);
                }
        } else {  // MODE 2: V^T [B,H,D,T], pack 4 consecutive t as ushort4
            unsigned short* C = (unsigned short*)Cout;
            const int h = gn >> 6, d = gn & 63;
#pragma unroll
            for (int m = 0; m < 4; ++m) {
                const int gm0 = row0 + wr + m * 16 + rq;     // multiple of 4, no b-cross
                const int b = gm0 >> 11, t0 = gm0 & (Tsz - 1);
                ushort4 u;
                u.x = f2bf(acc[m][n][0] + bv); u.y = f2bf(acc[m][n][1] + bv);
                u.z = f2bf(acc[m][n][2] + bv); u.w = f2bf(acc[m][n][3] + bv);
                *(ushort4*)&C[(((size_t)b * Hsz + h) * Dsz + d) * Tsz + t0] = u;
            }
        }
    }
}

// ---------------- flash attention: block = (b,h) x two paired Q-tiles of 64 rows
// q,k: [B,H,T,D] bf16   vt: [B,H,D,T] bf16   o16: [B*T, E] bf16
// faithful quirks: (s<=t && w!=0) ? w : -inf before softmax; final /8 after softmax
__global__ __launch_bounds__(256) void flash_attn_kernel(const unsigned short* __restrict__ q,
                                                         const unsigned short* __restrict__ k,
                                                         const unsigned short* __restrict__ vt,
                                                         unsigned short* __restrict__ o16) {
    constexpr int TS = 64, LDP = 72;                       // +8 pad: 16B-aligned rows, 2-way max conflicts
    __shared__ __align__(16) unsigned short Ks[TS * LDP];  // 9216 B
    __shared__ __align__(16) unsigned short Vs[Dsz * LDP]; // 9216 B
    __shared__ __align__(16) unsigned short Ps[4][16 * LDP]; // wave-private P tiles

    const int bh   = blockIdx.x >> 4;    // b*H + h
    const int pr   = blockIdx.x & 15;    // pair index
    const int tid  = threadIdx.x;
    const int lane = tid & 63;
    const int wid  = tid >> 6;
    const int fr   = lane & 15;
    const int kg   = lane >> 4;          // 0..3
    const int kh   = kg * 8;
    const int rq   = kg * 4;
    const int b    = bh >> 4, h = bh & (Hsz - 1);

    const size_t qkbase = (size_t)bh * Tsz * Dsz;
    const size_t vbase  = (size_t)bh * Dsz * Tsz;

    for (int half = 0; half < 2; ++half) {
        const int qt  = half ? (31 - pr) : pr;   // pairing (i, 31-i): 33 s-tiles per block
        const int q0  = qt * 64;
        const int q0w = q0 + wid * 16;

        // Q fragments (A-layout: row=fr, k=kh+0..7), once per Q-tile
        bf16x8 aq[2];
#pragma unroll
        for (int kk = 0; kk < 2; ++kk)
            aq[kk] = *(const bf16x8*)&q[qkbase + (size_t)(q0w + fr) * Dsz + kk * 32 + kh];

        float m[4], l[4];
        f32x4 oa[4] = {};
#pragma unroll
        for (int j = 0; j < 4; ++j) { m[j] = -INFINITY; l[j] = 0.0f; }

        for (int s0 = 0; s0 <= q0; s0 += TS) {
            __syncthreads();   // all waves done reading previous K/V tile
#pragma unroll
            for (int i = 0; i < 2; ++i) {      // 512 chunks of 8 bf16, 2 per thread
                const int c = tid + i * 256;
                const int r = c >> 3, col = (c & 7) * 8;
                *(bf16x8*)&Ks[r * LDP + col] = *(const bf16x8*)&k[qkbase + (size_t)(s0 + r) * Dsz + col];
                *(bf16x8*)&Vs[r * LDP + col] = *(const bf16x8*)&vt[vbase + (size_t)r * Tsz + s0 + col];
            }
            __syncthreads();

            // QK^T: C[q=rq+j (reg), s=n*16+fr (lane)]
            f32x4 acc[4] = {};
#pragma unroll
            for (int kk = 0; kk < 2; ++kk)
#pragma unroll
                for (int n = 0; n < 4; ++n) {
                    bf16x8 bk = *(const bf16x8*)&Ks[(n * 16 + fr) * LDP + kk * 32 + kh];
                    acc[n] = __builtin_amdgcn_mfma_f32_16x16x32_bf16(aq[kk], bk, acc[n], 0, 0, 0);
                }

            // mask + online softmax (row reductions across 16-lane groups)
#pragma unroll
            for (int j = 0; j < 4; ++j) {
                const int qrow = q0w + rq + j;
                float vmax = -INFINITY;
#pragma unroll
                for (int n = 0; n < 4; ++n) {
                    const int s = s0 + n * 16 + fr;
                    float val = acc[n][j];
                    val = (s <= qrow && val != 0.0f) ? val : -INFINITY;
                    acc[n][j] = val;
                    vmax = fmaxf(vmax, val);
                }
#pragma unroll
                for (int off = 1; off < 16; off <<= 1)
                    vmax = fmaxf(vmax, __shfl_xor(vmax, off, 64));
                const float mn = fmaxf(m[j], vmax);
                const float f  = expf(m[j] - mn);     // exp(-inf)=0 on first tile
                float rs = 0.0f;
#pragma unroll
                for (int n = 0; n < 4; ++n) {
                    const float p = expf(acc[n][j] - mn);
                    acc[n][j] = p;
                    rs += p;
                }
#pragma unroll
                for (int off = 1; off < 16; off <<= 1)
                    rs += __shfl_xor(rs, off, 64);
                l[j] = l[j] * f + rs;
                m[j] = mn;
#pragma unroll
                for (int dn = 0; dn < 4; ++dn) oa[dn][j] *= f;
            }

            // P -> LDS (wave-private; same-wave dep, no barrier needed)
#pragma unroll
            for (int j = 0; j < 4; ++j)
#pragma unroll
                for (int n = 0; n < 4; ++n)
                    Ps[wid][(rq + j) * LDP + n * 16 + fr] = f2bf(acc[n][j]);

            // PV: C[q, d] += P[q,s] * V^T[d,s]
#pragma unroll
            for (int kk = 0; kk < 2; ++kk) {
                bf16x8 ap = *(const bf16x8*)&Ps[wid][fr * LDP + kk * 32 + kh];
#pragma unroll
                for (int dn = 0; dn < 4; ++dn) {
                    bf16x8 bv = *(const bf16x8*)&Vs[(dn * 16 + fr) * LDP + kk * 32 + kh];
                    oa[dn] = __builtin_amdgcn_mfma_f32_16x16x32_bf16(ap, bv, oa[dn], 0, 0, 0);
                }
            }
        }

        // store: o[qrow, h*64+d] = oa / (l * 8)
#pragma unroll
        for (int j = 0; j < 4; ++j) {
            const int qrow = q0w + rq + j;
            const float inv = 1.0f / (l[j] * 8.0f);
#pragma unroll
            for (int dn = 0; dn < 4; ++dn)
                o16[((size_t)(b * Tsz + qrow)) * Esz + h * Dsz + dn * 16 + fr] = f2bf(oa[dn][j] * inv);
        }
    }
}

// ---------------- per-row NLL: rl[row] = lse(logits[row,:]) - logits[row,target]
__global__ __launch_bounds__(256) void rowloss_kernel(const float* __restrict__ logits,
                                                      const int* __restrict__ targets,
                                                      float* __restrict__ rl) {
    const int row = blockIdx.x;
    const float* lr = logits + (size_t)row * Vsz;
    __shared__ float red[256];
    const int tid = threadIdx.x;
    float m = -INFINITY;
    for (int i = tid; i < Vsz; i += 256) m = fmaxf(m, lr[i]);
    red[tid] = m; __syncthreads();
    for (int st = 128; st > 0; st >>= 1) { if (tid < st) red[tid] = fmaxf(red[tid], red[tid + st]); __syncthreads(); }
    m = red[0]; __syncthreads();
    float s = 0.0f;
    for (int i = tid; i < Vsz; i += 256) s += expf(lr[i] - m);
    red[tid] = s; __syncthreads();
    for (int st = 128; st > 0; st >>= 1) { if (tid < st) red[tid] += red[tid + st]; __syncthreads(); }
    if (tid == 0) rl[row] = (m + logf(red[0])) - lr[targets[row]];
}

__global__ __launch_bounds__(256) void loss_reduce_kernel(const float* __restrict__ rl,
                                                          float* __restrict__ out_loss) {
    __shared__ float red[256];
    const int tid = threadIdx.x;
    float s = 0.0f;
    for (int i = tid; i < BT; i += 256) s += rl[i];
    red[tid] = s; __syncthreads();
    for (int st = 128; st > 0; st >>= 1) { if (tid < st) red[tid] += red[tid + st]; __syncthreads(); }
    if (tid == 0) out_loss[0] = red[0] / (float)BT;
}

extern "C" void kernel_launch(void* const* d_in, const int* in_sizes, int n_in,
                              void* d_out, int out_size, void* d_ws, size_t ws_size,
                              hipStream_t stream) {
    const int*   tokens    = (const int*)d_in[0];
    const int*   targets   = (const int*)d_in[1];
    const float* tok_table = (const float*)d_in[2];
    const float* pos_emb   = (const float*)d_in[3];
    const float* Wq        = (const float*)d_in[4];
    const float* bq        = (const float*)d_in[5];
    const float* Wk        = (const float*)d_in[6];
    const float* bk        = (const float*)d_in[7];
    const float* Wv        = (const float*)d_in[8];
    const float* bv        = (const float*)d_in[9];
    const float* Wo        = (const float*)d_in[10];
    const float* bo        = (const float*)d_in[11];

    float* out    = (float*)d_out;
    float* logits = out;                              // [BT, V]
    float* loss   = out + (size_t)BT * Vsz;           // scalar

    char* p = (char*)d_ws;
    unsigned short* x16  = (unsigned short*)p; p += (size_t)BT * Esz * 2;   // 8 MB
    unsigned short* q16  = (unsigned short*)p; p += (size_t)BT * Esz * 2;   // 8 MB
    unsigned short* k16  = (unsigned short*)p; p += (size_t)BT * Esz * 2;   // 8 MB
    unsigned short* vt16 = (unsigned short*)p; p += (size_t)BT * Esz * 2;   // 8 MB (V^T)
    unsigned short* o16  = (unsigned short*)p; p += (size_t)BT * Esz * 2;   // 8 MB
    unsigned short* wq16 = (unsigned short*)p; p += (size_t)Esz * Esz * 2;  // 2 MB
    unsigned short* wk16 = (unsigned short*)p; p += (size_t)Esz * Esz * 2;  // 2 MB
    unsigned short* wv16 = (unsigned short*)p; p += (size_t)Esz * Esz * 2;  // 2 MB
    unsigned short* wo16 = (unsigned short*)p; p += (size_t)Vsz * Esz * 2;  // 65.5 MB
    float*          rl   = (float*)p;

    // 1) embedding (bf16 out) + weight casts
    embed_bf16_kernel<<<(BT * Esz / 4) / 256, 256, 0, stream>>>(tokens, tok_table, pos_emb, x16);
    cast_bf16_kernel<<<(Esz * Esz / 4) / 256, 256, 0, stream>>>(Wq, wq16, Esz * Esz / 4);
    cast_bf16_kernel<<<(Esz * Esz / 4) / 256, 256, 0, stream>>>(Wk, wk16, Esz * Esz / 4);
    cast_bf16_kernel<<<(Esz * Esz / 4) / 256, 256, 0, stream>>>(Wv, wv16, Esz * Esz / 4);
    cast_bf16_kernel<<<(Vsz * Esz / 4) / 256, 256, 0, stream>>>(Wo, wo16, Vsz * Esz / 4);

    // 2) QKV projections: q,k -> [B,H,T,D] bf16; v -> [B,H,D,T] bf16 (transposed)
    dim3 gqkv(Esz / 128, BT / 128);
    gemm_mfma<1><<<gqkv, 256, 0, stream>>>(x16, wq16, bq, q16, BT, Esz, Esz);
    gemm_mfma<1><<<gqkv, 256, 0, stream>>>(x16, wk16, bk, k16, BT, Esz, Esz);
    gemm_mfma<2><<<gqkv, 256, 0, stream>>>(x16, wv16, bv, vt16, BT, Esz, Esz);

    // 3) flash attention: 32 (b,h) x 16 balanced Q-tile pairs
    flash_attn_kernel<<<Bsz * Hsz * 16, 256, 0, stream>>>(q16, k16, vt16, o16);

    // 4) logits GEMM [BT,V] via bf16 MFMA
    dim3 glog(Vsz / 128, BT / 128);
    gemm_mfma<0><<<glog, 256, 0, stream>>>(o16, wo16, bo, logits, BT, Vsz, Esz);

    // 5) loss
    rowloss_kernel<<<BT, 256, 0, stream>>>(logits, targets, rl);
    loss_reduce_kernel<<<1, 256, 0, stream>>>(rl, loss);
}